// Round 6
// baseline (690.140 us; speedup 1.0000x reference)
//
#include <hip/hip_runtime.h>
#include <hip/hip_bf16.h>
#include <math.h>

typedef __bf16 bf16_t;
typedef __bf16 bf16x4_t __attribute__((ext_vector_type(4)));
typedef __bf16 bf16x8_t __attribute__((ext_vector_type(8)));
typedef float  f32x4_t  __attribute__((ext_vector_type(4)));

#define SEQ 2048
#define DM  1024
#define NH  16
#define DK  64
// log2(10000)/32
#define ROPE_C 0.4152410118609203f
// log2(e)/sqrt(dk)
#define EXP_C (1.4426950408889634f / 8.0f)

// ---------------- fused fp32 -> bf16 cast: x, wq, wk, wv, wo ----------------
__global__ __launch_bounds__(256)
void cast_all(const float* __restrict__ x,  const float* __restrict__ wq,
              const float* __restrict__ wk, const float* __restrict__ wv,
              const float* __restrict__ wo, bf16_t* __restrict__ dst) {
  int i = blockIdx.x * 256 + threadIdx.x;   // float4 index, 0..2097151
  const float* s;
  if (i < 1048576) {
    s = x + (size_t)i * 4;
  } else {
    int j = i - 1048576;
    int w = j >> 18;                        // 262144 float4 per weight
    const float* base = (w == 0) ? wq : (w == 1) ? wk : (w == 2) ? wv : wo;
    s = base + (size_t)(j & 262143) * 4;
  }
  float4 v = *(const float4*)s;
  bf16x4_t o;
  o.x = (bf16_t)v.x; o.y = (bf16_t)v.y; o.z = (bf16_t)v.z; o.w = (bf16_t)v.w;
  ((bf16x4_t*)dst)[i] = o;
}

// ---------------- fused QKV GEMM ----------------
// C[M=4096, N=3072] = x[M,K] * Wqkv[N,K]^T, K=1024. 128x128 tiles, 256 thr.
// bn 0..7: Q (RoPE) -> Qb (B,H,S,dk); bn 8..15: K (RoPE) -> Kb; bn 16..23: V -> Vtb (B,H,dk,S).
// NOTE: plain __launch_bounds__(256) ONLY. Any 2nd arg (tested 2 and 3 on this
// hipcc) caps VGPRs at 64 -> accumulator spill -> 1.6 GB scratch writes, 460 us
// (R4/R5 counters: VGPR_Count=60, WRITE_SIZE=1.58e6 KB both times).
__global__ __launch_bounds__(256)
void gemm_qkv(const bf16_t* __restrict__ A, const bf16_t* __restrict__ Bw,
              const float* __restrict__ bq, const float* __restrict__ bk,
              const float* __restrict__ bv,
              bf16_t* __restrict__ Qb, bf16_t* __restrict__ Kb, bf16_t* __restrict__ Vtb) {
  const int K = 1024;
  __shared__ bf16_t As[128 * 40];
  __shared__ bf16_t Bs[128 * 40];

  const int tid  = threadIdx.x;
  const int w    = tid >> 6;
  const int lane = tid & 63;
  const int quad = lane >> 4;
  const int lrow = lane & 15;
  const int wm = (w >> 1) * 64, wn = (w & 1) * 64;
  const int bm = blockIdx.y, bn = blockIdx.x;

  const bf16_t* Ablk = A  + (size_t)(bm * 128) * K;
  const bf16_t* Bblk = Bw + (size_t)(bn * 128) * K;

  f32x4_t acc[4][4] = {};

  const int lr = tid >> 1;
  const int lc = (tid & 1) * 16;

  for (int k0 = 0; k0 < K; k0 += 32) {
    *(uint4*)(&As[lr * 40 + lc])     = *(const uint4*)(&Ablk[(size_t)lr * K + k0 + lc]);
    *(uint4*)(&As[lr * 40 + lc + 8]) = *(const uint4*)(&Ablk[(size_t)lr * K + k0 + lc + 8]);
    *(uint4*)(&Bs[lr * 40 + lc])     = *(const uint4*)(&Bblk[(size_t)lr * K + k0 + lc]);
    *(uint4*)(&Bs[lr * 40 + lc + 8]) = *(const uint4*)(&Bblk[(size_t)lr * K + k0 + lc + 8]);
    __syncthreads();

    bf16x8_t af[4], bf[4];
#pragma unroll
    for (int mi = 0; mi < 4; mi++)
      af[mi] = *(const bf16x8_t*)(&As[(wm + mi * 16 + lrow) * 40 + quad * 8]);
#pragma unroll
    for (int ni = 0; ni < 4; ni++)
      bf[ni] = *(const bf16x8_t*)(&Bs[(wn + ni * 16 + lrow) * 40 + quad * 8]);
#pragma unroll
    for (int mi = 0; mi < 4; mi++)
#pragma unroll
      for (int ni = 0; ni < 4; ni++)
        acc[mi][ni] = __builtin_amdgcn_mfma_f32_16x16x32_bf16(af[mi], bf[ni], acc[mi][ni], 0, 0, 0);
    __syncthreads();
  }

  const int brow = bm * 128 + wm;
  const int mid = bn >> 3;                   // 0=Q 1=K 2=V (block-uniform)
  const int cbase = (bn & 7) * 128 + wn;     // col within the 1024-wide matrix

  if (mid < 2) {
    bf16_t* D = (mid == 0) ? Qb : Kb;
    const float* bias = (mid == 0) ? bq : bk;
#pragma unroll
    for (int ni = 0; ni < 4; ni++) {
      const int col = cbase + ni * 16 + lrow;  // 0..1023
      const float bv = bias[col];
      const int t = col & 63;
      const int h = col >> 6;
      const float invf = exp2f(-ROPE_C * (float)(t >> 1));
#pragma unroll
      for (int mi = 0; mi < 4; mi++) {
        f32x4_t v = acc[mi][ni];
#pragma unroll
        for (int r = 0; r < 4; r++) {
          const int row = brow + mi * 16 + quad * 4 + r;  // token
          float val = v[r] + bv;
          const int s = row & (SEQ - 1);
          float ang = (float)s * invf;
          float sn, cs;
          sincosf(ang, &sn, &cs);
          float pv = __shfl_xor(val, 1);
          val = (t & 1) ? (val * cs + pv * sn) : (val * cs - pv * sn);
          const int b = row >> 11;
          const size_t o = (((size_t)(b * NH + h) * SEQ) + s) * DK + t;
          D[o] = (bf16_t)val;
        }
      }
    }
  } else {
    // V -> V^T (B,H,dk,S); 4 acc rows are consecutive tokens -> packed 8B store
#pragma unroll
    for (int ni = 0; ni < 4; ni++) {
      const int col = cbase + ni * 16 + lrow;  // feature 0..1023
      const float bvv = bv[col];
      const int d = col & 63, h = col >> 6;
#pragma unroll
      for (int mi = 0; mi < 4; mi++) {
        f32x4_t v = acc[mi][ni];
        const int row = brow + mi * 16 + quad * 4;  // token base (mult of 4)
        const int b = row >> 11, s = row & (SEQ - 1);
        bf16x4_t pv;
#pragma unroll
        for (int r = 0; r < 4; r++) pv[r] = (bf16_t)(v[r] + bvv);
        *(bf16x4_t*)(&Vtb[((size_t)((b * NH + h) * DK + d)) * SEQ + s]) = pv;
      }
    }
  }
}

// ---------------- output GEMM: out[M,N] = AO[M,K] * Wo[N,K]^T + bo ----------------
// 128(M)x64(N) tiles -> grid (16, 32) = 512 blocks. Plain launch_bounds (see above).
__global__ __launch_bounds__(256)
void gemm_out(const bf16_t* __restrict__ A, const bf16_t* __restrict__ Bw,
              const float* __restrict__ bias, float* __restrict__ D) {
  const int K = 1024;
  __shared__ bf16_t As[128 * 40];
  __shared__ bf16_t Bs[64 * 40];

  const int tid  = threadIdx.x;
  const int w    = tid >> 6;
  const int lane = tid & 63;
  const int quad = lane >> 4;
  const int lrow = lane & 15;
  const int wm = (w >> 1) * 64, wn = (w & 1) * 32;
  const int bm = blockIdx.y, bn = blockIdx.x;

  const bf16_t* Ablk = A  + (size_t)(bm * 128) * K;
  const bf16_t* Bblk = Bw + (size_t)(bn * 64) * K;

  f32x4_t acc[4][2] = {};

  const int lr = tid >> 1;
  const int lc = (tid & 1) * 16;
  const int lrB = tid >> 2;
  const int lcB = (tid & 3) * 8;

  for (int k0 = 0; k0 < K; k0 += 32) {
    *(uint4*)(&As[lr * 40 + lc])     = *(const uint4*)(&Ablk[(size_t)lr * K + k0 + lc]);
    *(uint4*)(&As[lr * 40 + lc + 8]) = *(const uint4*)(&Ablk[(size_t)lr * K + k0 + lc + 8]);
    *(uint4*)(&Bs[lrB * 40 + lcB])   = *(const uint4*)(&Bblk[(size_t)lrB * K + k0 + lcB]);
    __syncthreads();

    bf16x8_t af[4], bf[2];
#pragma unroll
    for (int mi = 0; mi < 4; mi++)
      af[mi] = *(const bf16x8_t*)(&As[(wm + mi * 16 + lrow) * 40 + quad * 8]);
#pragma unroll
    for (int ni = 0; ni < 2; ni++)
      bf[ni] = *(const bf16x8_t*)(&Bs[(wn + ni * 16 + lrow) * 40 + quad * 8]);
#pragma unroll
    for (int mi = 0; mi < 4; mi++)
#pragma unroll
      for (int ni = 0; ni < 2; ni++)
        acc[mi][ni] = __builtin_amdgcn_mfma_f32_16x16x32_bf16(af[mi], bf[ni], acc[mi][ni], 0, 0, 0);
    __syncthreads();
  }

#pragma unroll
  for (int ni = 0; ni < 2; ni++) {
    const int col = bn * 64 + wn + ni * 16 + lrow;
    const float bvv = bias[col];
#pragma unroll
    for (int mi = 0; mi < 4; mi++) {
      f32x4_t v = acc[mi][ni];
#pragma unroll
      for (int r = 0; r < 4; r++) {
        const int row = bm * 128 + wm + mi * 16 + quad * 4 + r;
        D[(size_t)row * DM + col] = v[r] + bvv;
      }
    }
  }
}

// ---------------- flash attention v3: no-max softmax, K-tile 128 ----------------
// Q,K bf16 (B,H,S,dk); Vt bf16 (B,H,dk,S). Grid: (S/128, B*H). 4 waves, 32 q/wave.
#define PSTRIDE 132
__global__ __launch_bounds__(256)
void attn_kernel(const bf16_t* __restrict__ Q, const bf16_t* __restrict__ K,
                 const bf16_t* __restrict__ Vt, bf16_t* __restrict__ AO) {
  __shared__ bf16_t Ks[128 * 72];        // [key][dk]
  __shared__ bf16_t Vs[64 * 136];        // [dk][key]
  __shared__ bf16_t Ps[4][32 * PSTRIDE]; // per-wave P

  const int tid  = threadIdx.x;
  const int w    = tid >> 6;
  const int lane = tid & 63;
  const int quad = lane >> 4;
  const int lrow = lane & 15;
  const int bh = blockIdx.y;
  const int q0 = blockIdx.x * 128 + w * 32;

  const bf16_t* Qh  = Q  + (size_t)bh * SEQ * DK;
  const bf16_t* Kh  = K  + (size_t)bh * SEQ * DK;
  const bf16_t* Vth = Vt + (size_t)bh * DK * SEQ;

  bf16x8_t qf[2][2];
#pragma unroll
  for (int mi = 0; mi < 2; mi++)
#pragma unroll
    for (int c = 0; c < 2; c++)
      qf[mi][c] = *(const bf16x8_t*)(&Qh[(size_t)(q0 + mi * 16 + lrow) * DK + c * 32 + quad * 8]);

  f32x4_t accO[2][4] = {};
  float lsum[2][4] = {};

  const int krow = tid >> 1;            // 0..127 (K staging)
  const int kcol = (tid & 1) * 32;
  const int vrow = tid >> 2;            // 0..63 (V staging)
  const int vcol = (tid & 3) * 32;

  bf16_t* Pw = &Ps[w][0];

  for (int kt = 0; kt < SEQ / 128; ++kt) {
    const int kb = kt * 128;
#pragma unroll
    for (int u = 0; u < 4; u++)
      *(uint4*)(&Ks[krow * 72 + kcol + u * 8]) = *(const uint4*)(&Kh[(size_t)(kb + krow) * DK + kcol + u * 8]);
#pragma unroll
    for (int u = 0; u < 4; u++)
      *(uint4*)(&Vs[vrow * 136 + vcol + u * 8]) = *(const uint4*)(&Vth[(size_t)vrow * SEQ + kb + vcol + u * 8]);
    __syncthreads();

    // S = Q K^T per 16-key tile; p = exp2(s*EXP_C) immediately (no max shift)
#pragma unroll
    for (int n = 0; n < 8; n++) {
      bf16x8_t kf0 = *(const bf16x8_t*)(&Ks[(n * 16 + lrow) * 72 + quad * 8]);
      bf16x8_t kf1 = *(const bf16x8_t*)(&Ks[(n * 16 + lrow) * 72 + 32 + quad * 8]);
#pragma unroll
      for (int mi = 0; mi < 2; mi++) {
        f32x4_t z = {};
        z = __builtin_amdgcn_mfma_f32_16x16x32_bf16(qf[mi][0], kf0, z, 0, 0, 0);
        z = __builtin_amdgcn_mfma_f32_16x16x32_bf16(qf[mi][1], kf1, z, 0, 0, 0);
#pragma unroll
        for (int r = 0; r < 4; r++) {
          float p = exp2f(z[r] * EXP_C);
          lsum[mi][r] += p;
          Pw[(mi * 16 + quad * 4 + r) * PSTRIDE + n * 16 + lrow] = (bf16_t)p;
        }
      }
    }

    // O += P V  (Ps is per-wave: no barrier needed, wave-internal lgkmcnt ordering)
#pragma unroll
    for (int c = 0; c < 4; c++) {
      bf16x8_t pf[2];
#pragma unroll
      for (int mi = 0; mi < 2; mi++) {
        const int base = (mi * 16 + lrow) * PSTRIDE + c * 32 + quad * 8;
        bf16x8_t t;
        *(bf16x4_t*)(&t)       = *(const bf16x4_t*)(&Pw[base]);
        *((bf16x4_t*)(&t) + 1) = *(const bf16x4_t*)(&Pw[base + 4]);
        pf[mi] = t;
      }
#pragma unroll
      for (int nt = 0; nt < 4; nt++) {
        bf16x8_t vf = *(const bf16x8_t*)(&Vs[(nt * 16 + lrow) * 136 + c * 32 + quad * 8]);
        accO[0][nt] = __builtin_amdgcn_mfma_f32_16x16x32_bf16(pf[0], vf, accO[0][nt], 0, 0, 0);
        accO[1][nt] = __builtin_amdgcn_mfma_f32_16x16x32_bf16(pf[1], vf, accO[1][nt], 0, 0, 0);
      }
    }
    __syncthreads();
  }

  // one deferred l-reduction over the 16 lrow lanes
#pragma unroll
  for (int mi = 0; mi < 2; mi++)
#pragma unroll
    for (int r = 0; r < 4; r++) {
      float l = lsum[mi][r];
#pragma unroll
      for (int off = 1; off < 16; off <<= 1) l += __shfl_xor(l, off);
      lsum[mi][r] = 1.0f / l;
    }

  const int b = bh >> 4, h = bh & 15;
#pragma unroll
  for (int mi = 0; mi < 2; mi++)
#pragma unroll
    for (int nt = 0; nt < 4; nt++)
#pragma unroll
      for (int r = 0; r < 4; r++) {
        const int srowq = q0 + mi * 16 + quad * 4 + r;
        const float val = accO[mi][nt][r] * lsum[mi][r];
        const size_t o = ((size_t)(b * SEQ + srowq)) * DM + h * DK + nt * 16 + lrow;
        AO[o] = (bf16_t)val;
      }
}

extern "C" void kernel_launch(void* const* d_in, const int* in_sizes, int n_in,
                              void* d_out, int out_size, void* d_ws, size_t ws_size,
                              hipStream_t stream) {
  const float* x  = (const float*)d_in[0];
  const float* wq = (const float*)d_in[1];
  const float* bq = (const float*)d_in[2];
  const float* wk = (const float*)d_in[3];
  const float* bk = (const float*)d_in[4];
  const float* wv = (const float*)d_in[5];
  const float* bv = (const float*)d_in[6];
  const float* wo = (const float*)d_in[7];
  const float* bo = (const float*)d_in[8];
  float* out = (float*)d_out;

  char* ws = (char*)d_ws;
  bf16_t* xb   = (bf16_t*)(ws);             // 8 MB
  bf16_t* wqkv = (bf16_t*)(ws + 8388608);   // 6 MB (wq|wk|wv stacked)
  bf16_t* wob  = (bf16_t*)(ws + 14680064);  // 2 MB
  bf16_t* Qb   = (bf16_t*)(ws + 16777216);  // 8 MB (B,H,S,dk)
  bf16_t* Kb   = (bf16_t*)(ws + 25165824);  // 8 MB (B,H,S,dk)
  bf16_t* Vtb  = (bf16_t*)(ws + 33554432);  // 8 MB (B,H,dk,S)
  bf16_t* AOb  = (bf16_t*)(ws + 41943040);  // 8 MB (B,S,D)

  cast_all<<<8192, 256, 0, stream>>>(x, wq, wk, wv, wo, xb);

  gemm_qkv<<<dim3(24, 32), 256, 0, stream>>>(xb, wqkv, bq, bk, bv, Qb, Kb, Vtb);

  attn_kernel<<<dim3(SEQ / 128, 2 * NH), 256, 0, stream>>>(Qb, Kb, Vtb, AOb);

  gemm_out<<<dim3(16, 32), 256, 0, stream>>>(AOb, wob, bo, out);
}

// Round 7
// 260.172 us; speedup vs baseline: 2.6526x; 2.6526x over previous
//
#include <hip/hip_runtime.h>
#include <hip/hip_bf16.h>
#include <math.h>

typedef __bf16 bf16_t;
typedef __bf16 bf16x4_t __attribute__((ext_vector_type(4)));
typedef __bf16 bf16x8_t __attribute__((ext_vector_type(8)));
typedef float  f32x4_t  __attribute__((ext_vector_type(4)));

#define SEQ 2048
#define DM  1024
#define NH  16
#define DK  64
// log2(10000)/32
#define ROPE_C 0.4152410118609203f
// log2(e)/sqrt(dk)
#define EXP_C (1.4426950408889634f / 8.0f)

// ---------------- fused fp32 -> bf16 cast: x, wq, wk, wv, wo ----------------
__global__ __launch_bounds__(256)
void cast_all(const float* __restrict__ x,  const float* __restrict__ wq,
              const float* __restrict__ wk, const float* __restrict__ wv,
              const float* __restrict__ wo, bf16_t* __restrict__ dst) {
  int i = blockIdx.x * 256 + threadIdx.x;   // float4 index, 0..2097151
  const float* s;
  if (i < 1048576) {
    s = x + (size_t)i * 4;
  } else {
    int j = i - 1048576;
    int w = j >> 18;                        // 262144 float4 per weight
    const float* base = (w == 0) ? wq : (w == 1) ? wk : (w == 2) ? wv : wo;
    s = base + (size_t)(j & 262143) * 4;
  }
  float4 v = *(const float4*)s;
  bf16x4_t o;
  o.x = (bf16_t)v.x; o.y = (bf16_t)v.y; o.z = (bf16_t)v.z; o.w = (bf16_t)v.w;
  ((bf16x4_t*)dst)[i] = o;
}

// ---------------- RoPE sin/cos LUT: lut[s*32+f] = (sin, cos)(s * base^(-f/32)) ----
__global__ __launch_bounds__(256)
void rope_lut_kernel(float2* __restrict__ lut) {
  int i = blockIdx.x * 256 + threadIdx.x;   // 0..65535
  int s = i >> 5, f = i & 31;
  float ang = (float)s * exp2f(-ROPE_C * (float)f);
  float sn, cs;
  sincosf(ang, &sn, &cs);
  lut[i] = make_float2(sn, cs);
}

// ---------------- Q/K GEMM with fused RoPE ----------------
// C = x[M,K] * W[N,K]^T + bias, M=4096, N=1024 each for Q and K.
// Grid (16, 32): bn 0..7 -> Q (wqb, bq -> Qb), bn 8..15 -> K. 128x128 tiles.
// NOTE: single epilogue path, no libm calls. The merged 3-path epilogue with
// inline sincosf (R4-R6) made the compiler allocate only 64 VGPRs and spill
// acc to scratch (1.6 GB writes, 460-500 us). Keep epilogues minimal.
// NOTE: plain __launch_bounds__(256) only (no 2nd arg).
__global__ __launch_bounds__(256)
void gemm_qk(const bf16_t* __restrict__ A, const bf16_t* __restrict__ Wq,
             const bf16_t* __restrict__ Wk, const float* __restrict__ bq,
             const float* __restrict__ bk, const float2* __restrict__ lut,
             bf16_t* __restrict__ Qb, bf16_t* __restrict__ Kb) {
  const int K = 1024;
  __shared__ bf16_t As[128 * 40];
  __shared__ bf16_t Bs[128 * 40];

  const int tid  = threadIdx.x;
  const int w    = tid >> 6;
  const int lane = tid & 63;
  const int quad = lane >> 4;
  const int lrow = lane & 15;
  const int wm = (w >> 1) * 64, wn = (w & 1) * 64;
  const int bm = blockIdx.y, bn = blockIdx.x;

  const int isK = bn >> 3;                  // 0 = Q, 1 = K (block-uniform)
  const int bnl = bn & 7;
  const bf16_t* Ablk = A + (size_t)(bm * 128) * K;
  const bf16_t* Bblk = (isK ? Wk : Wq) + (size_t)(bnl * 128) * K;
  const float*  bias = isK ? bk : bq;
  bf16_t* D = isK ? Kb : Qb;

  f32x4_t acc[4][4] = {};

  const int lr = tid >> 1;
  const int lc = (tid & 1) * 16;

  for (int k0 = 0; k0 < K; k0 += 32) {
    *(uint4*)(&As[lr * 40 + lc])     = *(const uint4*)(&Ablk[(size_t)lr * K + k0 + lc]);
    *(uint4*)(&As[lr * 40 + lc + 8]) = *(const uint4*)(&Ablk[(size_t)lr * K + k0 + lc + 8]);
    *(uint4*)(&Bs[lr * 40 + lc])     = *(const uint4*)(&Bblk[(size_t)lr * K + k0 + lc]);
    *(uint4*)(&Bs[lr * 40 + lc + 8]) = *(const uint4*)(&Bblk[(size_t)lr * K + k0 + lc + 8]);
    __syncthreads();

    bf16x8_t af[4], bf[4];
#pragma unroll
    for (int mi = 0; mi < 4; mi++)
      af[mi] = *(const bf16x8_t*)(&As[(wm + mi * 16 + lrow) * 40 + quad * 8]);
#pragma unroll
    for (int ni = 0; ni < 4; ni++)
      bf[ni] = *(const bf16x8_t*)(&Bs[(wn + ni * 16 + lrow) * 40 + quad * 8]);
#pragma unroll
    for (int mi = 0; mi < 4; mi++)
#pragma unroll
      for (int ni = 0; ni < 4; ni++)
        acc[mi][ni] = __builtin_amdgcn_mfma_f32_16x16x32_bf16(af[mi], bf[ni], acc[mi][ni], 0, 0, 0);
    __syncthreads();
  }

  const int brow = bm * 128 + wm;
  const int cbase = bnl * 128 + wn;

#pragma unroll
  for (int ni = 0; ni < 4; ni++) {
    const int col = cbase + ni * 16 + lrow;  // 0..1023
    const float bv = bias[col];
    const int t = col & 63;
    const int h = col >> 6;
    const int fidx = t >> 1;
#pragma unroll
    for (int mi = 0; mi < 4; mi++) {
      f32x4_t v = acc[mi][ni];
#pragma unroll
      for (int r = 0; r < 4; r++) {
        const int row = brow + mi * 16 + quad * 4 + r;  // token
        const int s = row & (SEQ - 1);
        float val = v[r] + bv;
        const float2 sc = lut[s * 32 + fidx];
        const float pv = __shfl_xor(val, 1);            // partner column col^1
        val = (t & 1) ? (val * sc.y + pv * sc.x) : (val * sc.y - pv * sc.x);
        const int b = row >> 11;
        const size_t o = (((size_t)(b * NH + h) * SEQ) + s) * DK + t;
        D[o] = (bf16_t)val;
      }
    }
  }
}

// ---------------- V^T GEMM: Vt = (x Wv^T + bv)^T in (B,H,dk,S) ----------------
// A = Wv (rows=features), B = x (rows=tokens). Grid (32, 8).
__global__ __launch_bounds__(256)
void gemm_vt(const bf16_t* __restrict__ A, const bf16_t* __restrict__ Bx,
             const float* __restrict__ bias, bf16_t* __restrict__ Vtb) {
  const int K = 1024;
  __shared__ bf16_t As[128 * 40];
  __shared__ bf16_t Bs[128 * 40];

  const int tid  = threadIdx.x;
  const int w    = tid >> 6;
  const int lane = tid & 63;
  const int quad = lane >> 4;
  const int lrow = lane & 15;
  const int wm = (w >> 1) * 64, wn = (w & 1) * 64;
  const int bm = blockIdx.y, bn = blockIdx.x;

  const bf16_t* Ablk = A  + (size_t)(bm * 128) * K;   // features
  const bf16_t* Bblk = Bx + (size_t)(bn * 128) * K;   // tokens

  f32x4_t acc[4][4] = {};

  const int lr = tid >> 1;
  const int lc = (tid & 1) * 16;

  for (int k0 = 0; k0 < K; k0 += 32) {
    *(uint4*)(&As[lr * 40 + lc])     = *(const uint4*)(&Ablk[(size_t)lr * K + k0 + lc]);
    *(uint4*)(&As[lr * 40 + lc + 8]) = *(const uint4*)(&Ablk[(size_t)lr * K + k0 + lc + 8]);
    *(uint4*)(&Bs[lr * 40 + lc])     = *(const uint4*)(&Bblk[(size_t)lr * K + k0 + lc]);
    *(uint4*)(&Bs[lr * 40 + lc + 8]) = *(const uint4*)(&Bblk[(size_t)lr * K + k0 + lc + 8]);
    __syncthreads();

    bf16x8_t af[4], bf[4];
#pragma unroll
    for (int mi = 0; mi < 4; mi++)
      af[mi] = *(const bf16x8_t*)(&As[(wm + mi * 16 + lrow) * 40 + quad * 8]);
#pragma unroll
    for (int ni = 0; ni < 4; ni++)
      bf[ni] = *(const bf16x8_t*)(&Bs[(wn + ni * 16 + lrow) * 40 + quad * 8]);
#pragma unroll
    for (int mi = 0; mi < 4; mi++)
#pragma unroll
      for (int ni = 0; ni < 4; ni++)
        acc[mi][ni] = __builtin_amdgcn_mfma_f32_16x16x32_bf16(af[mi], bf[ni], acc[mi][ni], 0, 0, 0);
    __syncthreads();
  }

  const int fbase = bm * 128 + wm;
  const int tbase = bn * 128 + wn;

#pragma unroll
  for (int ni = 0; ni < 4; ni++) {
    const int t = tbase + ni * 16 + lrow;    // token 0..4095
    const int b = t >> 11;
    const int s = t & (SEQ - 1);
#pragma unroll
    for (int mi = 0; mi < 4; mi++) {
      f32x4_t v = acc[mi][ni];
      const int f = fbase + mi * 16 + quad * 4;  // feature base (mult of 4)
      const int h = f >> 6, d = f & 63;
      // NOTE: rows (r) are consecutive FEATURES here, tokens are per-lane ->
      // scalar stores (feature-major Vt layout); 4 stores per (mi,ni)
#pragma unroll
      for (int r = 0; r < 4; r++)
        Vtb[((size_t)((b * NH + h) * DK + d + r)) * SEQ + s] = (bf16_t)(v[r] + bias[f + r]);
    }
  }
}

// ---------------- output GEMM: out[M,N] = AO[M,K] * Wo[N,K]^T + bo ----------------
// 128(M)x64(N) tiles -> grid (16, 32) = 512 blocks.
__global__ __launch_bounds__(256)
void gemm_out(const bf16_t* __restrict__ A, const bf16_t* __restrict__ Bw,
              const float* __restrict__ bias, float* __restrict__ D) {
  const int K = 1024;
  __shared__ bf16_t As[128 * 40];
  __shared__ bf16_t Bs[64 * 40];

  const int tid  = threadIdx.x;
  const int w    = tid >> 6;
  const int lane = tid & 63;
  const int quad = lane >> 4;
  const int lrow = lane & 15;
  const int wm = (w >> 1) * 64, wn = (w & 1) * 32;
  const int bm = blockIdx.y, bn = blockIdx.x;

  const bf16_t* Ablk = A  + (size_t)(bm * 128) * K;
  const bf16_t* Bblk = Bw + (size_t)(bn * 64) * K;

  f32x4_t acc[4][2] = {};

  const int lr = tid >> 1;
  const int lc = (tid & 1) * 16;
  const int lrB = tid >> 2;
  const int lcB = (tid & 3) * 8;

  for (int k0 = 0; k0 < K; k0 += 32) {
    *(uint4*)(&As[lr * 40 + lc])     = *(const uint4*)(&Ablk[(size_t)lr * K + k0 + lc]);
    *(uint4*)(&As[lr * 40 + lc + 8]) = *(const uint4*)(&Ablk[(size_t)lr * K + k0 + lc + 8]);
    *(uint4*)(&Bs[lrB * 40 + lcB])   = *(const uint4*)(&Bblk[(size_t)lrB * K + k0 + lcB]);
    __syncthreads();

    bf16x8_t af[4], bf[2];
#pragma unroll
    for (int mi = 0; mi < 4; mi++)
      af[mi] = *(const bf16x8_t*)(&As[(wm + mi * 16 + lrow) * 40 + quad * 8]);
#pragma unroll
    for (int ni = 0; ni < 2; ni++)
      bf[ni] = *(const bf16x8_t*)(&Bs[(wn + ni * 16 + lrow) * 40 + quad * 8]);
#pragma unroll
    for (int mi = 0; mi < 4; mi++)
#pragma unroll
      for (int ni = 0; ni < 2; ni++)
        acc[mi][ni] = __builtin_amdgcn_mfma_f32_16x16x32_bf16(af[mi], bf[ni], acc[mi][ni], 0, 0, 0);
    __syncthreads();
  }

#pragma unroll
  for (int ni = 0; ni < 2; ni++) {
    const int col = bn * 64 + wn + ni * 16 + lrow;
    const float bvv = bias[col];
#pragma unroll
    for (int mi = 0; mi < 4; mi++) {
      f32x4_t v = acc[mi][ni];
#pragma unroll
      for (int r = 0; r < 4; r++) {
        const int row = bm * 128 + wm + mi * 16 + quad * 4 + r;
        D[(size_t)row * DM + col] = v[r] + bvv;
      }
    }
  }
}

// ---------------- flash attention v3: no-max softmax, K-tile 128 ----------------
// Q,K bf16 (B,H,S,dk); Vt bf16 (B,H,dk,S). Grid: (S/128, B*H). 4 waves, 32 q/wave.
#define PSTRIDE 132
__global__ __launch_bounds__(256)
void attn_kernel(const bf16_t* __restrict__ Q, const bf16_t* __restrict__ K,
                 const bf16_t* __restrict__ Vt, bf16_t* __restrict__ AO) {
  __shared__ bf16_t Ks[128 * 72];        // [key][dk]
  __shared__ bf16_t Vs[64 * 136];        // [dk][key]
  __shared__ bf16_t Ps[4][32 * PSTRIDE]; // per-wave P

  const int tid  = threadIdx.x;
  const int w    = tid >> 6;
  const int lane = tid & 63;
  const int quad = lane >> 4;
  const int lrow = lane & 15;
  const int bh = blockIdx.y;
  const int q0 = blockIdx.x * 128 + w * 32;

  const bf16_t* Qh  = Q  + (size_t)bh * SEQ * DK;
  const bf16_t* Kh  = K  + (size_t)bh * SEQ * DK;
  const bf16_t* Vth = Vt + (size_t)bh * DK * SEQ;

  bf16x8_t qf[2][2];
#pragma unroll
  for (int mi = 0; mi < 2; mi++)
#pragma unroll
    for (int c = 0; c < 2; c++)
      qf[mi][c] = *(const bf16x8_t*)(&Qh[(size_t)(q0 + mi * 16 + lrow) * DK + c * 32 + quad * 8]);

  f32x4_t accO[2][4] = {};
  float lsum[2][4] = {};

  const int krow = tid >> 1;            // 0..127 (K staging)
  const int kcol = (tid & 1) * 32;
  const int vrow = tid >> 2;            // 0..63 (V staging)
  const int vcol = (tid & 3) * 32;

  bf16_t* Pw = &Ps[w][0];

  for (int kt = 0; kt < SEQ / 128; ++kt) {
    const int kb = kt * 128;
#pragma unroll
    for (int u = 0; u < 4; u++)
      *(uint4*)(&Ks[krow * 72 + kcol + u * 8]) = *(const uint4*)(&Kh[(size_t)(kb + krow) * DK + kcol + u * 8]);
#pragma unroll
    for (int u = 0; u < 4; u++)
      *(uint4*)(&Vs[vrow * 136 + vcol + u * 8]) = *(const uint4*)(&Vth[(size_t)vrow * SEQ + kb + vcol + u * 8]);
    __syncthreads();

    // S = Q K^T per 16-key tile; p = exp2(s*EXP_C) immediately (no max shift)
#pragma unroll
    for (int n = 0; n < 8; n++) {
      bf16x8_t kf0 = *(const bf16x8_t*)(&Ks[(n * 16 + lrow) * 72 + quad * 8]);
      bf16x8_t kf1 = *(const bf16x8_t*)(&Ks[(n * 16 + lrow) * 72 + 32 + quad * 8]);
#pragma unroll
      for (int mi = 0; mi < 2; mi++) {
        f32x4_t z = {};
        z = __builtin_amdgcn_mfma_f32_16x16x32_bf16(qf[mi][0], kf0, z, 0, 0, 0);
        z = __builtin_amdgcn_mfma_f32_16x16x32_bf16(qf[mi][1], kf1, z, 0, 0, 0);
#pragma unroll
        for (int r = 0; r < 4; r++) {
          float p = exp2f(z[r] * EXP_C);
          lsum[mi][r] += p;
          Pw[(mi * 16 + quad * 4 + r) * PSTRIDE + n * 16 + lrow] = (bf16_t)p;
        }
      }
    }

    // O += P V  (Ps is per-wave: no barrier needed, wave-internal lgkmcnt ordering)
#pragma unroll
    for (int c = 0; c < 4; c++) {
      bf16x8_t pf[2];
#pragma unroll
      for (int mi = 0; mi < 2; mi++) {
        const int base = (mi * 16 + lrow) * PSTRIDE + c * 32 + quad * 8;
        bf16x8_t t;
        *(bf16x4_t*)(&t)       = *(const bf16x4_t*)(&Pw[base]);
        *((bf16x4_t*)(&t) + 1) = *(const bf16x4_t*)(&Pw[base + 4]);
        pf[mi] = t;
      }
#pragma unroll
      for (int nt = 0; nt < 4; nt++) {
        bf16x8_t vf = *(const bf16x8_t*)(&Vs[(nt * 16 + lrow) * 136 + c * 32 + quad * 8]);
        accO[0][nt] = __builtin_amdgcn_mfma_f32_16x16x32_bf16(pf[0], vf, accO[0][nt], 0, 0, 0);
        accO[1][nt] = __builtin_amdgcn_mfma_f32_16x16x32_bf16(pf[1], vf, accO[1][nt], 0, 0, 0);
      }
    }
    __syncthreads();
  }

  // one deferred l-reduction over the 16 lrow lanes
#pragma unroll
  for (int mi = 0; mi < 2; mi++)
#pragma unroll
    for (int r = 0; r < 4; r++) {
      float l = lsum[mi][r];
#pragma unroll
      for (int off = 1; off < 16; off <<= 1) l += __shfl_xor(l, off);
      lsum[mi][r] = 1.0f / l;
    }

  const int b = bh >> 4, h = bh & 15;
#pragma unroll
  for (int mi = 0; mi < 2; mi++)
#pragma unroll
    for (int nt = 0; nt < 4; nt++)
#pragma unroll
      for (int r = 0; r < 4; r++) {
        const int srowq = q0 + mi * 16 + quad * 4 + r;
        const float val = accO[mi][nt][r] * lsum[mi][r];
        const size_t o = ((size_t)(b * SEQ + srowq)) * DM + h * DK + nt * 16 + lrow;
        AO[o] = (bf16_t)val;
      }
}

extern "C" void kernel_launch(void* const* d_in, const int* in_sizes, int n_in,
                              void* d_out, int out_size, void* d_ws, size_t ws_size,
                              hipStream_t stream) {
  const float* x  = (const float*)d_in[0];
  const float* wq = (const float*)d_in[1];
  const float* bq = (const float*)d_in[2];
  const float* wk = (const float*)d_in[3];
  const float* bk = (const float*)d_in[4];
  const float* wv = (const float*)d_in[5];
  const float* bv = (const float*)d_in[6];
  const float* wo = (const float*)d_in[7];
  const float* bo = (const float*)d_in[8];
  float* out = (float*)d_out;

  char* ws = (char*)d_ws;
  bf16_t* xb   = (bf16_t*)(ws);             // 8 MB
  bf16_t* wqb  = (bf16_t*)(ws + 8388608);   // 2 MB
  bf16_t* wkb  = (bf16_t*)(ws + 10485760);  // 2 MB
  bf16_t* wvb  = (bf16_t*)(ws + 12582912);  // 2 MB
  bf16_t* wob  = (bf16_t*)(ws + 14680064);  // 2 MB
  bf16_t* Qb   = (bf16_t*)(ws + 16777216);  // 8 MB (B,H,S,dk)
  bf16_t* Kb   = (bf16_t*)(ws + 25165824);  // 8 MB (B,H,S,dk)
  bf16_t* Vtb  = (bf16_t*)(ws + 33554432);  // 8 MB (B,H,dk,S)
  bf16_t* AOb  = (bf16_t*)(ws + 41943040);  // 8 MB (B,S,D)
  float2* lut  = (float2*)(ws + 50331648);  // 512 KB RoPE LUT

  cast_all<<<8192, 256, 0, stream>>>(x, wq, wk, wv, wo, xb);
  rope_lut_kernel<<<256, 256, 0, stream>>>(lut);

  gemm_qk<<<dim3(16, 32), 256, 0, stream>>>(xb, wqb, wkb, bq, bk, lut, Qb, Kb);
  gemm_vt<<<dim3(32, 8), 256, 0, stream>>>(wvb, xb, bv, Vtb);

  attn_kernel<<<dim3(SEQ / 128, 2 * NH), 256, 0, stream>>>(Qb, Kb, Vtb, AOb);

  gemm_out<<<dim3(16, 32), 256, 0, stream>>>(AOb, wob, bo, out);
}

// Round 8
// 244.794 us; speedup vs baseline: 2.8193x; 1.0628x over previous
//
#include <hip/hip_runtime.h>
#include <hip/hip_bf16.h>
#include <math.h>

typedef __bf16 bf16_t;
typedef __bf16 bf16x4_t __attribute__((ext_vector_type(4)));
typedef __bf16 bf16x8_t __attribute__((ext_vector_type(8)));
typedef float  f32x4_t  __attribute__((ext_vector_type(4)));

#define SEQ 2048
#define DM  1024
#define NH  16
#define DK  64
// log2(10000)/32
#define ROPE_C 0.4152410118609203f
// log2(e)/sqrt(dk)
#define EXP_C (1.4426950408889634f / 8.0f)

// ---------------- fused fp32 -> bf16 cast: x, wq, wk, wv, wo ----------------
__global__ __launch_bounds__(256)
void cast_all(const float* __restrict__ x,  const float* __restrict__ wq,
              const float* __restrict__ wk, const float* __restrict__ wv,
              const float* __restrict__ wo, bf16_t* __restrict__ dst) {
  int i = blockIdx.x * 256 + threadIdx.x;   // float4 index, 0..2097151
  const float* s;
  if (i < 1048576) {
    s = x + (size_t)i * 4;
  } else {
    int j = i - 1048576;
    int w = j >> 18;                        // 262144 float4 per weight
    const float* base = (w == 0) ? wq : (w == 1) ? wk : (w == 2) ? wv : wo;
    s = base + (size_t)(j & 262143) * 4;
  }
  float4 v = *(const float4*)s;
  bf16x4_t o;
  o.x = (bf16_t)v.x; o.y = (bf16_t)v.y; o.z = (bf16_t)v.z; o.w = (bf16_t)v.w;
  ((bf16x4_t*)dst)[i] = o;
}

// ---------------- RoPE sin/cos LUT: lut[s*32+f] = (sin, cos)(s * base^(-f/32)) ----
__global__ __launch_bounds__(256)
void rope_lut_kernel(float2* __restrict__ lut) {
  int i = blockIdx.x * 256 + threadIdx.x;   // 0..65535
  int s = i >> 5, f = i & 31;
  float ang = (float)s * exp2f(-ROPE_C * (float)f);
  float sn, cs;
  sincosf(ang, &sn, &cs);
  lut[i] = make_float2(sn, cs);
}

// ---------------- Q/K GEMM with fused RoPE ----------------
// Grid (16, 32): bn 0..7 -> Q, bn 8..15 -> K. 128x128 tiles.
// NOTE: single epilogue path, no libm calls (multi-path epilogue + inline
// sincosf caused 64-VGPR alloc + acc spill, R4-R6). Plain launch_bounds only.
__global__ __launch_bounds__(256)
void gemm_qk(const bf16_t* __restrict__ A, const bf16_t* __restrict__ Wq,
             const bf16_t* __restrict__ Wk, const float* __restrict__ bq,
             const float* __restrict__ bk, const float2* __restrict__ lut,
             bf16_t* __restrict__ Qb, bf16_t* __restrict__ Kb) {
  const int K = 1024;
  __shared__ bf16_t As[128 * 40];
  __shared__ bf16_t Bs[128 * 40];

  const int tid  = threadIdx.x;
  const int w    = tid >> 6;
  const int lane = tid & 63;
  const int quad = lane >> 4;
  const int lrow = lane & 15;
  const int wm = (w >> 1) * 64, wn = (w & 1) * 64;
  const int bm = blockIdx.y, bn = blockIdx.x;

  const int isK = bn >> 3;                  // 0 = Q, 1 = K (block-uniform)
  const int bnl = bn & 7;
  const bf16_t* Ablk = A + (size_t)(bm * 128) * K;
  const bf16_t* Bblk = (isK ? Wk : Wq) + (size_t)(bnl * 128) * K;
  const float*  bias = isK ? bk : bq;
  bf16_t* D = isK ? Kb : Qb;

  f32x4_t acc[4][4] = {};

  const int lr = tid >> 1;
  const int lc = (tid & 1) * 16;

  for (int k0 = 0; k0 < K; k0 += 32) {
    *(uint4*)(&As[lr * 40 + lc])     = *(const uint4*)(&Ablk[(size_t)lr * K + k0 + lc]);
    *(uint4*)(&As[lr * 40 + lc + 8]) = *(const uint4*)(&Ablk[(size_t)lr * K + k0 + lc + 8]);
    *(uint4*)(&Bs[lr * 40 + lc])     = *(const uint4*)(&Bblk[(size_t)lr * K + k0 + lc]);
    *(uint4*)(&Bs[lr * 40 + lc + 8]) = *(const uint4*)(&Bblk[(size_t)lr * K + k0 + lc + 8]);
    __syncthreads();

    bf16x8_t af[4], bf[4];
#pragma unroll
    for (int mi = 0; mi < 4; mi++)
      af[mi] = *(const bf16x8_t*)(&As[(wm + mi * 16 + lrow) * 40 + quad * 8]);
#pragma unroll
    for (int ni = 0; ni < 4; ni++)
      bf[ni] = *(const bf16x8_t*)(&Bs[(wn + ni * 16 + lrow) * 40 + quad * 8]);
#pragma unroll
    for (int mi = 0; mi < 4; mi++)
#pragma unroll
      for (int ni = 0; ni < 4; ni++)
        acc[mi][ni] = __builtin_amdgcn_mfma_f32_16x16x32_bf16(af[mi], bf[ni], acc[mi][ni], 0, 0, 0);
    __syncthreads();
  }

  const int brow = bm * 128 + wm;
  const int cbase = bnl * 128 + wn;

#pragma unroll
  for (int ni = 0; ni < 4; ni++) {
    const int col = cbase + ni * 16 + lrow;  // 0..1023
    const float bv = bias[col];
    const int t = col & 63;
    const int h = col >> 6;
    const int fidx = t >> 1;
#pragma unroll
    for (int mi = 0; mi < 4; mi++) {
      f32x4_t v = acc[mi][ni];
#pragma unroll
      for (int r = 0; r < 4; r++) {
        const int row = brow + mi * 16 + quad * 4 + r;  // token
        const int s = row & (SEQ - 1);
        float val = v[r] + bv;
        const float2 sc = lut[s * 32 + fidx];
        const float pv = __shfl_xor(val, 1);            // partner column col^1
        val = (t & 1) ? (val * sc.y + pv * sc.x) : (val * sc.y - pv * sc.x);
        const int b = row >> 11;
        const size_t o = (((size_t)(b * NH + h) * SEQ) + s) * DK + t;
        D[o] = (bf16_t)val;
      }
    }
  }
}

// ---------------- V^T GEMM: Vt = (x Wv^T + bv)^T in (B,H,dk,S) ----------------
// A = Wv (rows=features), B = x (rows=tokens). 64(f)x128(t) tiles -> grid
// (32, 16) = 512 blocks = 2/CU (R7's 128x128 grid was 256 blocks = 1/CU).
__global__ __launch_bounds__(256)
void gemm_vt(const bf16_t* __restrict__ A, const bf16_t* __restrict__ Bx,
             const float* __restrict__ bias, bf16_t* __restrict__ Vtb) {
  const int K = 1024;
  __shared__ bf16_t As[64 * 40];
  __shared__ bf16_t Bs[128 * 40];

  const int tid  = threadIdx.x;
  const int w    = tid >> 6;
  const int lane = tid & 63;
  const int quad = lane >> 4;
  const int lrow = lane & 15;
  const int wm = (w >> 1) * 32, wn = (w & 1) * 64;
  const int bm = blockIdx.y, bn = blockIdx.x;

  const bf16_t* Ablk = A  + (size_t)(bm * 64) * K;    // features
  const bf16_t* Bblk = Bx + (size_t)(bn * 128) * K;   // tokens

  f32x4_t acc[2][4] = {};

  const int lrA = tid >> 2;
  const int lcA = (tid & 3) * 8;
  const int lrB = tid >> 1;
  const int lcB = (tid & 1) * 16;

  for (int k0 = 0; k0 < K; k0 += 32) {
    *(uint4*)(&As[lrA * 40 + lcA])    = *(const uint4*)(&Ablk[(size_t)lrA * K + k0 + lcA]);
    *(uint4*)(&Bs[lrB * 40 + lcB])    = *(const uint4*)(&Bblk[(size_t)lrB * K + k0 + lcB]);
    *(uint4*)(&Bs[lrB * 40 + lcB + 8])= *(const uint4*)(&Bblk[(size_t)lrB * K + k0 + lcB + 8]);
    __syncthreads();

    bf16x8_t af[2], bf[4];
#pragma unroll
    for (int mi = 0; mi < 2; mi++)
      af[mi] = *(const bf16x8_t*)(&As[(wm + mi * 16 + lrow) * 40 + quad * 8]);
#pragma unroll
    for (int ni = 0; ni < 4; ni++)
      bf[ni] = *(const bf16x8_t*)(&Bs[(wn + ni * 16 + lrow) * 40 + quad * 8]);
#pragma unroll
    for (int mi = 0; mi < 2; mi++)
#pragma unroll
      for (int ni = 0; ni < 4; ni++)
        acc[mi][ni] = __builtin_amdgcn_mfma_f32_16x16x32_bf16(af[mi], bf[ni], acc[mi][ni], 0, 0, 0);
    __syncthreads();
  }

  const int fbase = bm * 64 + wm;
  const int tbase = bn * 128 + wn;

#pragma unroll
  for (int ni = 0; ni < 4; ni++) {
    const int t = tbase + ni * 16 + lrow;    // token 0..4095
    const int b = t >> 11;
    const int s = t & (SEQ - 1);
#pragma unroll
    for (int mi = 0; mi < 2; mi++) {
      f32x4_t v = acc[mi][ni];
      const int f = fbase + mi * 16 + quad * 4;  // feature base (mult of 4)
      const int h = f >> 6, d = f & 63;
#pragma unroll
      for (int r = 0; r < 4; r++)
        Vtb[((size_t)((b * NH + h) * DK + d + r)) * SEQ + s] = (bf16_t)(v[r] + bias[f + r]);
    }
  }
}

// ---------------- output GEMM: out[M,N] = AO[M,K] * Wo[N,K]^T + bo ----------------
__global__ __launch_bounds__(256)
void gemm_out(const bf16_t* __restrict__ A, const bf16_t* __restrict__ Bw,
              const float* __restrict__ bias, float* __restrict__ D) {
  const int K = 1024;
  __shared__ bf16_t As[128 * 40];
  __shared__ bf16_t Bs[64 * 40];

  const int tid  = threadIdx.x;
  const int w    = tid >> 6;
  const int lane = tid & 63;
  const int quad = lane >> 4;
  const int lrow = lane & 15;
  const int wm = (w >> 1) * 64, wn = (w & 1) * 32;
  const int bm = blockIdx.y, bn = blockIdx.x;

  const bf16_t* Ablk = A  + (size_t)(bm * 128) * K;
  const bf16_t* Bblk = Bw + (size_t)(bn * 64) * K;

  f32x4_t acc[4][2] = {};

  const int lr = tid >> 1;
  const int lc = (tid & 1) * 16;
  const int lrB = tid >> 2;
  const int lcB = (tid & 3) * 8;

  for (int k0 = 0; k0 < K; k0 += 32) {
    *(uint4*)(&As[lr * 40 + lc])     = *(const uint4*)(&Ablk[(size_t)lr * K + k0 + lc]);
    *(uint4*)(&As[lr * 40 + lc + 8]) = *(const uint4*)(&Ablk[(size_t)lr * K + k0 + lc + 8]);
    *(uint4*)(&Bs[lrB * 40 + lcB])   = *(const uint4*)(&Bblk[(size_t)lrB * K + k0 + lcB]);
    __syncthreads();

    bf16x8_t af[4], bf[2];
#pragma unroll
    for (int mi = 0; mi < 4; mi++)
      af[mi] = *(const bf16x8_t*)(&As[(wm + mi * 16 + lrow) * 40 + quad * 8]);
#pragma unroll
    for (int ni = 0; ni < 2; ni++)
      bf[ni] = *(const bf16x8_t*)(&Bs[(wn + ni * 16 + lrow) * 40 + quad * 8]);
#pragma unroll
    for (int mi = 0; mi < 4; mi++)
#pragma unroll
      for (int ni = 0; ni < 2; ni++)
        acc[mi][ni] = __builtin_amdgcn_mfma_f32_16x16x32_bf16(af[mi], bf[ni], acc[mi][ni], 0, 0, 0);
    __syncthreads();
  }

#pragma unroll
  for (int ni = 0; ni < 2; ni++) {
    const int col = bn * 64 + wn + ni * 16 + lrow;
    const float bvv = bias[col];
#pragma unroll
    for (int mi = 0; mi < 4; mi++) {
      f32x4_t v = acc[mi][ni];
#pragma unroll
      for (int r = 0; r < 4; r++) {
        const int row = bm * 128 + wm + mi * 16 + quad * 4 + r;
        D[(size_t)row * DM + col] = v[r] + bvv;
      }
    }
  }
}

// ---------------- flash attention v4: S^T + permuted-key PV, no P round-trip ----
// S^T = mfma(A=K-frag, B=Q-frag) -> C-layout (q=lane&15, key=quad*4+r), which IS
// the PV A-operand layout under the per-32-key permutation
// kslot(quad,j) -> key 16*(j>=4) + quad*4 + (j&3). V B-frags read the same
// permuted order from Vs via two b64 loads. Zero P LDS traffic; Ps buffer gone
// (LDS 69.6->35.8 KB => 4 blocks/CU). Softmax scale folded into Q frags.
__global__ __launch_bounds__(256)
void attn_kernel(const bf16_t* __restrict__ Q, const bf16_t* __restrict__ K,
                 const bf16_t* __restrict__ Vt, bf16_t* __restrict__ AO) {
  __shared__ bf16_t Ks[128 * 72];        // [key][dk]
  __shared__ bf16_t Vs[64 * 136];        // [dk][key]

  const int tid  = threadIdx.x;
  const int w    = tid >> 6;
  const int lane = tid & 63;
  const int quad = lane >> 4;
  const int lrow = lane & 15;
  const int bh = blockIdx.y;
  const int q0 = blockIdx.x * 128 + w * 32;

  const bf16_t* Qh  = Q  + (size_t)bh * SEQ * DK;
  const bf16_t* Kh  = K  + (size_t)bh * SEQ * DK;
  const bf16_t* Vth = Vt + (size_t)bh * DK * SEQ;

  // Q fragments, pre-scaled by EXP_C (B-operand of S^T mfma)
  bf16x8_t qf[2][2];
#pragma unroll
  for (int mi = 0; mi < 2; mi++)
#pragma unroll
    for (int c = 0; c < 2; c++) {
      bf16x8_t t = *(const bf16x8_t*)(&Qh[(size_t)(q0 + mi * 16 + lrow) * DK + c * 32 + quad * 8]);
#pragma unroll
      for (int i = 0; i < 8; i++) t[i] = (bf16_t)((float)t[i] * EXP_C);
      qf[mi][c] = t;
    }

  f32x4_t accO[2][4] = {};
  float lsum[2] = {0.f, 0.f};

  const int krow = tid >> 1;            // 0..127 (K staging)
  const int kcol = (tid & 1) * 32;
  const int vrow = tid >> 2;            // 0..63 (V staging)
  const int vcol = (tid & 3) * 32;

  for (int kt = 0; kt < SEQ / 128; ++kt) {
    const int kb = kt * 128;
#pragma unroll
    for (int u = 0; u < 4; u++)
      *(uint4*)(&Ks[krow * 72 + kcol + u * 8]) = *(const uint4*)(&Kh[(size_t)(kb + krow) * DK + kcol + u * 8]);
#pragma unroll
    for (int u = 0; u < 4; u++)
      *(uint4*)(&Vs[vrow * 136 + vcol + u * 8]) = *(const uint4*)(&Vth[(size_t)vrow * SEQ + kb + vcol + u * 8]);
    __syncthreads();

#pragma unroll
    for (int c2 = 0; c2 < 4; ++c2) {        // 32-key chunk
      bf16x4_t pk[2][2];                    // [kk2][mi]
#pragma unroll
      for (int kk2 = 0; kk2 < 2; ++kk2) {
        const int kk = c2 * 2 + kk2;        // 16-key tile
        bf16x8_t kf0 = *(const bf16x8_t*)(&Ks[(kk * 16 + lrow) * 72 + quad * 8]);
        bf16x8_t kf1 = *(const bf16x8_t*)(&Ks[(kk * 16 + lrow) * 72 + 32 + quad * 8]);
#pragma unroll
        for (int mi = 0; mi < 2; ++mi) {
          f32x4_t z = {};
          z = __builtin_amdgcn_mfma_f32_16x16x32_bf16(kf0, qf[mi][0], z, 0, 0, 0);
          z = __builtin_amdgcn_mfma_f32_16x16x32_bf16(kf1, qf[mi][1], z, 0, 0, 0);
          const float p0 = exp2f(z[0]), p1 = exp2f(z[1]);
          const float p2 = exp2f(z[2]), p3 = exp2f(z[3]);
          lsum[mi] += (p0 + p1) + (p2 + p3);
          bf16x4_t pv;
          pv[0] = (bf16_t)p0; pv[1] = (bf16_t)p1; pv[2] = (bf16_t)p2; pv[3] = (bf16_t)p3;
          pk[kk2][mi] = pv;
        }
      }
      bf16x8_t pf[2];
#pragma unroll
      for (int mi = 0; mi < 2; ++mi) {
        *(bf16x4_t*)(&pf[mi])       = pk[0][mi];
        *((bf16x4_t*)(&pf[mi]) + 1) = pk[1][mi];
      }
#pragma unroll
      for (int nt = 0; nt < 4; ++nt) {
        const bf16_t* vbase = &Vs[(nt * 16 + lrow) * 136 + c2 * 32 + quad * 4];
        bf16x8_t vf;
        *(bf16x4_t*)(&vf)       = *(const bf16x4_t*)(vbase);
        *((bf16x4_t*)(&vf) + 1) = *(const bf16x4_t*)(vbase + 16);
        accO[0][nt] = __builtin_amdgcn_mfma_f32_16x16x32_bf16(pf[0], vf, accO[0][nt], 0, 0, 0);
        accO[1][nt] = __builtin_amdgcn_mfma_f32_16x16x32_bf16(pf[1], vf, accO[1][nt], 0, 0, 0);
      }
    }
    __syncthreads();
  }

  // lsum lives at (q = lane&15); reduce over the 4 quads
#pragma unroll
  for (int mi = 0; mi < 2; mi++) {
    lsum[mi] += __shfl_xor(lsum[mi], 16);
    lsum[mi] += __shfl_xor(lsum[mi], 32);
  }
  // accO rows are q_local = quad*4+r -> pull lsum from lane quad*4+r
  float linv[2][4];
#pragma unroll
  for (int mi = 0; mi < 2; mi++)
#pragma unroll
    for (int r = 0; r < 4; r++)
      linv[mi][r] = 1.0f / __shfl(lsum[mi], quad * 4 + r);

  const int b = bh >> 4, h = bh & 15;
#pragma unroll
  for (int mi = 0; mi < 2; mi++)
#pragma unroll
    for (int nt = 0; nt < 4; nt++)
#pragma unroll
      for (int r = 0; r < 4; r++) {
        const int srowq = q0 + mi * 16 + quad * 4 + r;
        const float val = accO[mi][nt][r] * linv[mi][r];
        const size_t o = ((size_t)(b * SEQ + srowq)) * DM + h * DK + nt * 16 + lrow;
        AO[o] = (bf16_t)val;
      }
}

extern "C" void kernel_launch(void* const* d_in, const int* in_sizes, int n_in,
                              void* d_out, int out_size, void* d_ws, size_t ws_size,
                              hipStream_t stream) {
  const float* x  = (const float*)d_in[0];
  const float* wq = (const float*)d_in[1];
  const float* bq = (const float*)d_in[2];
  const float* wk = (const float*)d_in[3];
  const float* bk = (const float*)d_in[4];
  const float* wv = (const float*)d_in[5];
  const float* bv = (const float*)d_in[6];
  const float* wo = (const float*)d_in[7];
  const float* bo = (const float*)d_in[8];
  float* out = (float*)d_out;

  char* ws = (char*)d_ws;
  bf16_t* xb   = (bf16_t*)(ws);             // 8 MB
  bf16_t* wqb  = (bf16_t*)(ws + 8388608);   // 2 MB
  bf16_t* wkb  = (bf16_t*)(ws + 10485760);  // 2 MB
  bf16_t* wvb  = (bf16_t*)(ws + 12582912);  // 2 MB
  bf16_t* wob  = (bf16_t*)(ws + 14680064);  // 2 MB
  bf16_t* Qb   = (bf16_t*)(ws + 16777216);  // 8 MB (B,H,S,dk)
  bf16_t* Kb   = (bf16_t*)(ws + 25165824);  // 8 MB (B,H,S,dk)
  bf16_t* Vtb  = (bf16_t*)(ws + 33554432);  // 8 MB (B,H,dk,S)
  bf16_t* AOb  = (bf16_t*)(ws + 41943040);  // 8 MB (B,S,D)
  float2* lut  = (float2*)(ws + 50331648);  // 512 KB RoPE LUT

  cast_all<<<8192, 256, 0, stream>>>(x, wq, wk, wv, wo, xb);
  rope_lut_kernel<<<256, 256, 0, stream>>>(lut);

  gemm_qk<<<dim3(16, 32), 256, 0, stream>>>(xb, wqb, wkb, bq, bk, lut, Qb, Kb);
  gemm_vt<<<dim3(32, 16), 256, 0, stream>>>(wvb, xb, bv, Vtb);

  attn_kernel<<<dim3(SEQ / 128, 2 * NH), 256, 0, stream>>>(Qb, Kb, Vtb, AOb);

  gemm_out<<<dim3(16, 32), 256, 0, stream>>>(AOb, wob, bo, out);
}